// Round 5
// baseline (3160.545 us; speedup 1.0000x reference)
//
#include <hip/hip_runtime.h>

#define N_TOK 32768
#define DIM 512
#define K_CODES 4096
#define TOK_B 64
#define BK 128
#define BD 16
#define NCH (DIM / BD)      // 32 chunks
#define SPLIT_CH 24         // d=384 boundary: OpenBLAS zen/haswell SGEMM_DEFAULT_Q=384

// ---------------- x2 = numpy pairwise-sum replica (npyv AVX512 path) ----------------
// np.sum(flat*flat, axis=1): squares rounded separately (__fmul_rn), then
// pairwise_sum(512) = ((B0+B1)+(B2+B3)) over 128-blocks; each 128-block via
// 8x 16-lane vectors: lanewise tree ((r0+r1)+(r2+r3))+((r4+r5)+(r6+r7)),
// then horizontal halving reduce (L,L+8)(L,L+4)(L,L+2)(L,L+1).
__global__ __launch_bounds__(256) void vq_x2(const float* __restrict__ X, float* __restrict__ X2) {
    int n = blockIdx.x * 256 + threadIdx.x;
    const float* xr = X + (size_t)n * DIM;
    float blk[4];
    #pragma unroll
    for (int b = 0; b < 4; ++b) {
        const float* p = xr + b * 128;
        float lane[16];
        #pragma unroll
        for (int L = 0; L < 16; ++L) {
            float s[8];
            #pragma unroll
            for (int r = 0; r < 8; ++r) {
                float x = p[r * 16 + L];
                s[r] = __fmul_rn(x, x);
            }
            float a01 = __fadd_rn(s[0], s[1]);
            float a23 = __fadd_rn(s[2], s[3]);
            float a45 = __fadd_rn(s[4], s[5]);
            float a67 = __fadd_rn(s[6], s[7]);
            lane[L] = __fadd_rn(__fadd_rn(a01, a23), __fadd_rn(a45, a67));
        }
        float t[8];
        #pragma unroll
        for (int L = 0; L < 8; ++L) t[L] = __fadd_rn(lane[L], lane[L + 8]);
        float u[4];
        #pragma unroll
        for (int L = 0; L < 4; ++L) u[L] = __fadd_rn(t[L], t[L + 4]);
        float v0 = __fadd_rn(u[0], u[2]);
        float v1 = __fadd_rn(u[1], u[3]);
        blk[b] = __fadd_rn(v0, v1);
    }
    X2[n] = __fadd_rn(__fadd_rn(blk[0], blk[1]), __fadd_rn(blk[2], blk[3]));
}

// ---------------- np-f32-replicating argmin ----------------
// C[n,k]: OpenBLAS sgemm replica = fl( fmaf-chain(d=0..383) + fmaf-chain(d=384..511) ),
// each chain single f32 accumulator, ascending d (microkernel K-loop), split at Q=384.
// Distance D = RN(x2[n] - 2*C) == fmaf(-2, C, x2)  (2C exact; fl(x2+e2)==x2 since
// e2 ~1e-5 < half-ulp(x2~512); e2 drops out of the reference entirely).
// argmin: np first-index semantics via strict < with per-thread ascending k +
// lexicographic (v, id) cross-lane reduce.
__global__ __launch_bounds__(256) void vq_np2(const float* __restrict__ X,
        const float* __restrict__ CB, const float* __restrict__ X2,
        unsigned* __restrict__ idxA) {
    __shared__ __align__(16) float es[BD][BK];   // 8 KB

    const int t = threadIdx.x;
    const int ty = t >> 4;          // 0..15 -> tokens ty*4 .. ty*4+3
    const int tx = t & 15;          // 0..15 -> codes tx*4..+3 and 64+tx*4..+3
    const int n0 = blockIdx.x * TOK_B;
    const int srow = t >> 1;        // staging: code row 0..127
    const int scol = (t & 1) * 8;   // staging: dim offset 0 or 8

    const float* xrow0 = X + (size_t)(n0 + ty * 4) * DIM;

    float x2v[4];
    #pragma unroll
    for (int i = 0; i < 4; ++i) x2v[i] = X2[n0 + ty * 4 + i];

    float best[4];
    unsigned bid[4];
    #pragma unroll
    for (int i = 0; i < 4; ++i) { best[i] = 3.0e38f; bid[i] = 0u; }

    // prefetch first staging chunk (kt=0, ch=0)
    float pv[8];
    {
        const float* p = CB + (size_t)srow * DIM + scol;
        *(float4*)&pv[0] = *(const float4*)(p);
        *(float4*)&pv[4] = *(const float4*)(p + 4);
    }

    for (int kt = 0; kt < K_CODES; kt += BK) {
        float accA[4][8], accB[4][8];
        #pragma unroll
        for (int i = 0; i < 4; ++i)
            #pragma unroll
            for (int j = 0; j < 8; ++j) { accA[i][j] = 0.f; accB[i][j] = 0.f; }

        for (int ch = 0; ch < NCH; ++ch) {
            const int dt = ch * BD;
            float4 xv[4][4];
            #pragma unroll
            for (int i = 0; i < 4; ++i)
                #pragma unroll
                for (int u = 0; u < 4; ++u)
                    xv[i][u] = *(const float4*)(xrow0 + (size_t)i * DIM + dt + u * 4);

            __syncthreads();
            #pragma unroll
            for (int q = 0; q < 8; ++q) es[scol + q][srow] = pv[q];
            int nkt = kt, nch = ch + 1;
            if (nch == NCH) { nch = 0; nkt += BK; }
            if (nkt < K_CODES) {
                const float* p = CB + (size_t)(nkt + srow) * DIM + nch * BD + scol;
                *(float4*)&pv[0] = *(const float4*)(p);
                *(float4*)&pv[4] = *(const float4*)(p + 4);
            }
            __syncthreads();

            if (ch < SPLIT_CH) {
                #pragma unroll
                for (int d = 0; d < BD; ++d) {
                    const float4 e0 = *(const float4*)&es[d][tx * 4];
                    const float4 e1 = *(const float4*)&es[d][tx * 4 + 64];
                    const float eb[8] = {e0.x, e0.y, e0.z, e0.w, e1.x, e1.y, e1.z, e1.w};
                    #pragma unroll
                    for (int i = 0; i < 4; ++i) {
                        const float xd = ((const float*)&xv[i][0])[d];
                        #pragma unroll
                        for (int j = 0; j < 8; ++j)
                            accA[i][j] = fmaf(xd, eb[j], accA[i][j]);
                    }
                }
            } else {
                #pragma unroll
                for (int d = 0; d < BD; ++d) {
                    const float4 e0 = *(const float4*)&es[d][tx * 4];
                    const float4 e1 = *(const float4*)&es[d][tx * 4 + 64];
                    const float eb[8] = {e0.x, e0.y, e0.z, e0.w, e1.x, e1.y, e1.z, e1.w};
                    #pragma unroll
                    for (int i = 0; i < 4; ++i) {
                        const float xd = ((const float*)&xv[i][0])[d];
                        #pragma unroll
                        for (int j = 0; j < 8; ++j)
                            accB[i][j] = fmaf(xd, eb[j], accB[i][j]);
                    }
                }
            }
        }

        // finalize tile: C = fl(chainA + chainB); D = RN(x2 - 2C); ascending k, strict <
        #pragma unroll
        for (int j = 0; j < 8; ++j) {
            const int k = kt + ((j < 4) ? (tx * 4 + j) : (64 + tx * 4 + j - 4));
            #pragma unroll
            for (int i = 0; i < 4; ++i) {
                float C = __fadd_rn(accA[i][j], accB[i][j]);
                float v = fmaf(-2.0f, C, x2v[i]);
                if (v < best[i]) { best[i] = v; bid[i] = (unsigned)k; }
            }
        }
    }

    // lexicographic (v, id) reduce over the 16 tx lanes
    #pragma unroll
    for (int i = 0; i < 4; ++i) {
        float v = best[i];
        unsigned id = bid[i];
        #pragma unroll
        for (int m = 1; m < 16; m <<= 1) {
            float ov = __shfl_xor(v, m);
            unsigned oid = __shfl_xor(id, m);
            if (ov < v || (ov == v && oid < id)) { v = ov; id = oid; }
        }
        if (tx == 0) idxA[n0 + ty * 4 + i] = id;
    }
}

// ---------------- gather + straight-through + loss partials ----------------
__global__ __launch_bounds__(256) void vq_out(const float* __restrict__ X,
        const float* __restrict__ CB, const unsigned* __restrict__ idxA,
        float* __restrict__ outq, float* __restrict__ outidx, float* __restrict__ lossAcc) {
    int tid = threadIdx.x;
    int token = blockIdx.x * 16 + (tid >> 4);
    int chunk = tid & 15;
    unsigned k = idxA[token];
    const float4* q4 = (const float4*)(CB + (size_t)k * DIM + chunk * 32);
    const float4* x4 = (const float4*)(X + (size_t)token * DIM + chunk * 32);
    float4* o4 = (float4*)(outq + (size_t)token * DIM + chunk * 32);
    float ls = 0.f;
    #pragma unroll
    for (int u = 0; u < 8; ++u) {
        float4 q = q4[u], xx = x4[u];
        float dx = q.x - xx.x, dy = q.y - xx.y, dz = q.z - xx.z, dw = q.w - xx.w;
        float4 o;
        o.x = xx.x + dx; o.y = xx.y + dy; o.z = xx.z + dz; o.w = xx.w + dw;
        o4[u] = o;
        ls += dx*dx + dy*dy + dz*dz + dw*dw;
    }
    if (chunk == 0) outidx[token] = (float)k;
    #pragma unroll
    for (int m = 1; m < 64; m <<= 1) ls += __shfl_xor(ls, m);
    __shared__ float red[4];
    if ((tid & 63) == 0) red[tid >> 6] = ls;
    __syncthreads();
    if (tid == 0) atomicAdd(lossAcc, red[0] + red[1] + red[2] + red[3]);
}

__global__ void vq_fin(const float* __restrict__ lossAcc, float* __restrict__ outloss) {
    *outloss = 1.1f * (*lossAcc) * (1.0f / 16777216.0f);
}

extern "C" void kernel_launch(void* const* d_in, const int* in_sizes, int n_in,
                              void* d_out, int out_size, void* d_ws, size_t ws_size,
                              hipStream_t stream) {
    const float* X  = (const float*)d_in[0];
    const float* CB = (const float*)d_in[1];
    float* out = (float*)d_out;
    float* outq    = out;
    float* outloss = out + (size_t)N_TOK * DIM;
    float* outidx  = out + (size_t)N_TOK * DIM + 1;

    char* w = (char*)d_ws;
    float* lossAcc  = (float*)(w + 4);
    float* X2       = (float*)(w + 64);                  // 32768 f32
    unsigned* idxA  = (unsigned*)(w + 64 + 131072);      // 32768 u32

    hipMemsetAsync(d_ws, 0, 64, stream);
    vq_x2<<<N_TOK / 256, 256, 0, stream>>>(X, X2);
    vq_np2<<<N_TOK / TOK_B, 256, 0, stream>>>(X, CB, X2, idxA);
    vq_out<<<N_TOK / 16, 256, 0, stream>>>(X, CB, idxA, outq, outidx, lossAcc);
    vq_fin<<<1, 1, 0, stream>>>(lossAcc, outloss);
}

// Round 7
// 903.399 us; speedup vs baseline: 3.4985x; 3.4985x over previous
//
#include <hip/hip_runtime.h>

#define N_TOK 32768
#define DIM 512
#define K_CODES 4096
#define KP 1536
#define CMARG 8e-5f

typedef __attribute__((ext_vector_type(8))) short bf16x8;
typedef __attribute__((ext_vector_type(4))) float f32x4;

__device__ __forceinline__ unsigned short f2bf(float f) {           // RNE, bit-level
    unsigned u = __float_as_uint(f);
    return (unsigned short)((u + 0x7FFFu + ((u >> 16) & 1u)) >> 16);
}
__device__ __forceinline__ float bf2f(unsigned short h) {
    return __uint_as_float((unsigned)h << 16);
}
__device__ __forceinline__ void gld16(const void* g, void* l) {
    __builtin_amdgcn_global_load_lds((const __attribute__((address_space(1))) void*)g,
                                     (__attribute__((address_space(3))) void*)l, 16, 0, 0);
}

// ---------------- x2 = numpy pairwise-sum replica (validated round 5) ----------------
__global__ __launch_bounds__(256) void vq_x2(const float* __restrict__ X, float* __restrict__ X2) {
    int n = blockIdx.x * 256 + threadIdx.x;
    const float* xr = X + (size_t)n * DIM;
    float blk[4];
    #pragma unroll
    for (int b = 0; b < 4; ++b) {
        const float* p = xr + b * 128;
        float lane[16];
        #pragma unroll
        for (int L = 0; L < 16; ++L) {
            float s[8];
            #pragma unroll
            for (int r = 0; r < 8; ++r) { float x = p[r * 16 + L]; s[r] = __fmul_rn(x, x); }
            float a01 = __fadd_rn(s[0], s[1]);
            float a23 = __fadd_rn(s[2], s[3]);
            float a45 = __fadd_rn(s[4], s[5]);
            float a67 = __fadd_rn(s[6], s[7]);
            lane[L] = __fadd_rn(__fadd_rn(a01, a23), __fadd_rn(a45, a67));
        }
        float t[8];
        #pragma unroll
        for (int L = 0; L < 8; ++L) t[L] = __fadd_rn(lane[L], lane[L + 8]);
        float u[4];
        #pragma unroll
        for (int L = 0; L < 4; ++L) u[L] = __fadd_rn(t[L], t[L + 4]);
        blk[b] = __fadd_rn(__fadd_rn(u[0], u[2]), __fadd_rn(u[1], u[3]));
    }
    X2[n] = __fadd_rn(__fadd_rn(blk[0], blk[1]), __fadd_rn(blk[2], blk[3]));
}

// ---------------- bf16 hi/lo split of X and CB ----------------
__global__ __launch_bounds__(256) void vq_split(const float* __restrict__ X, const float* __restrict__ CB,
        unsigned short* __restrict__ Ah, unsigned short* __restrict__ Al,
        unsigned short* __restrict__ Eh, unsigned short* __restrict__ El) {
    size_t idx = ((size_t)blockIdx.x * 256 + threadIdx.x) * 8;
    const size_t XE = (size_t)N_TOK * DIM;
    const float* src;
    unsigned short *dh, *dl;
    size_t off;
    if (idx < XE) { src = X + idx; dh = Ah; dl = Al; off = idx; }
    else          { src = CB + (idx - XE); dh = Eh; dl = El; off = idx - XE; }
    float4 v0 = *(const float4*)src;
    float4 v1 = *(const float4*)(src + 4);
    float xv[8] = {v0.x, v0.y, v0.z, v0.w, v1.x, v1.y, v1.z, v1.w};
    union { unsigned short u[8]; uint4 v; } H, L;
    #pragma unroll
    for (int u = 0; u < 8; ++u) {
        unsigned short hb = f2bf(xv[u]);
        H.u[u] = hb;
        L.u[u] = f2bf(__fadd_rn(xv[u], -bf2f(hb)));
    }
    *(uint4*)(dh + off) = H.v;
    *(uint4*)(dl + off) = L.v;
}

// ---------------- bf16 MFMA GEMM (K'=1536 via [Ah,Al,Ah]x[Eh,Eh,El]) + tile-max/mask epilogue ----------------
__global__ __launch_bounds__(256, 2) void vq_gemm(
        const unsigned short* __restrict__ Ah, const unsigned short* __restrict__ Al,
        const unsigned short* __restrict__ Eh, const unsigned short* __restrict__ El,
        float* __restrict__ Cm, unsigned* __restrict__ Mk) {
    __shared__ __align__(16) unsigned short As[8192];   // [128][64] bf16, source-swizzled, 16 KB
    __shared__ __align__(16) unsigned short Bs[8192];
    __shared__ float redbuf[2][128];
    __shared__ float tmax[128];
    __shared__ unsigned maskLDS[128][4];

    const int tid = threadIdx.x;
    const int lane = tid & 63;
    const int w = tid >> 6;
    const int wr = w >> 1, wc = w & 1;
    const int bm = blockIdx.x;          // token tile 0..255
    const int bn = blockIdx.y;          // code tile 0..31

    const int srow = tid >> 3;                       // staging row 0..31 within issue
    const int scol_s = ((tid & 7) * 16) ^ (((tid >> 3) & 7) << 4);   // swizzled source byte col

    f32x4 acc[4][4];
    #pragma unroll
    for (int i = 0; i < 4; ++i)
        #pragma unroll
        for (int j = 0; j < 4; ++j) acc[i][j] = (f32x4){0.f, 0.f, 0.f, 0.f};

    const int arow = (lane & 15);                   // frag row/col within 16
    const int kqb  = (lane >> 4) * 16;              // frag k-group byte offset (8 bf16)

    for (int kt = 0; kt < KP / 64; ++kt) {
        const int kk = kt * 64;
        const int seg = kk >> 9;
        const int kin = kk & 511;
        const unsigned short* Asrc = (seg == 1) ? Al : Ah;
        const unsigned short* Bsrc = (seg == 2) ? El : Eh;
        __syncthreads();
        #pragma unroll
        for (int it = 0; it < 4; ++it) {
            const int row = it * 32 + srow;
            const char* ga = (const char*)Asrc + (size_t)(bm * 128 + row) * 1024 + kin * 2 + scol_s;
            const char* gb = (const char*)Bsrc + (size_t)(bn * 128 + row) * 1024 + kin * 2 + scol_s;
            char* la = (char*)As + it * 4096 + w * 1024;
            char* lb = (char*)Bs + it * 4096 + w * 1024;
            gld16(ga, la);
            gld16(gb, lb);
        }
        asm volatile("s_waitcnt vmcnt(0)" ::: "memory");
        __syncthreads();
        #pragma unroll
        for (int ks = 0; ks < 2; ++ks) {
            bf16x8 a[4], b[4];
            const int kb = ks * 64 + kqb;           // byte col 0..112 (BUGFIX: was ks*32)
            #pragma unroll
            for (int i = 0; i < 4; ++i) {
                int row = wr * 64 + i * 16 + arow;
                a[i] = *(const bf16x8*)((const char*)As + row * 128 + (kb ^ ((row & 7) << 4)));
            }
            #pragma unroll
            for (int j = 0; j < 4; ++j) {
                int row = wc * 64 + j * 16 + arow;
                b[j] = *(const bf16x8*)((const char*)Bs + row * 128 + (kb ^ ((row & 7) << 4)));
            }
            #pragma unroll
            for (int i = 0; i < 4; ++i)
                #pragma unroll
                for (int j = 0; j < 4; ++j)
                    acc[i][j] = __builtin_amdgcn_mfma_f32_16x16x32_bf16(a[i], b[j], acc[i][j], 0, 0, 0);
        }
    }

    // epilogue: per-row tile max + candidate bitmask
    float vmax[4][4];
    #pragma unroll
    for (int i = 0; i < 4; ++i)
        #pragma unroll
        for (int r = 0; r < 4; ++r) {
            float m = acc[i][0][r];
            m = fmaxf(m, acc[i][1][r]);
            m = fmaxf(m, acc[i][2][r]);
            m = fmaxf(m, acc[i][3][r]);
            #pragma unroll
            for (int s = 1; s < 16; s <<= 1) m = fmaxf(m, __shfl_xor(m, s));
            vmax[i][r] = m;
        }
    if (tid < 128) { maskLDS[tid][0] = 0; maskLDS[tid][1] = 0; maskLDS[tid][2] = 0; maskLDS[tid][3] = 0; }
    if ((lane & 15) == 0) {
        #pragma unroll
        for (int i = 0; i < 4; ++i)
            #pragma unroll
            for (int r = 0; r < 4; ++r)
                redbuf[wc][wr * 64 + i * 16 + (lane >> 4) * 4 + r] = vmax[i][r];
    }
    __syncthreads();
    if (tid < 128) {
        float tm = fmaxf(redbuf[0][tid], redbuf[1][tid]);
        tmax[tid] = tm;
        Cm[(size_t)(bm * 128 + tid) * 32 + bn] = tm;
    }
    __syncthreads();
    #pragma unroll
    for (int i = 0; i < 4; ++i)
        #pragma unroll
        for (int r = 0; r < 4; ++r) {
            int row = wr * 64 + i * 16 + (lane >> 4) * 4 + r;
            float thr = tmax[row] - CMARG;
            #pragma unroll
            for (int j = 0; j < 4; ++j) {
                if (acc[i][j][r] >= thr) {
                    int col = wc * 64 + j * 16 + (lane & 15);
                    atomicOr(&maskLDS[row][col >> 5], 1u << (col & 31));
                }
            }
        }
    __syncthreads();
    if (tid < 128) {
        uint4 v = make_uint4(maskLDS[tid][0], maskLDS[tid][1], maskLDS[tid][2], maskLDS[tid][3]);
        *(uint4*)&Mk[((size_t)(bm * 128 + tid) * 32 + bn) * 4] = v;
    }
}

// ---------------- row scan: qualify tiles within margin of row max ----------------
__global__ __launch_bounds__(256) void vq_scan(const float* __restrict__ Cm,
        unsigned* __restrict__ list, unsigned* __restrict__ cnt) {
    int n = blockIdx.x * 256 + threadIdx.x;
    const float4* cp = (const float4*)(Cm + (size_t)n * 32);
    float vals[32];
    float m = -3e38f;
    #pragma unroll
    for (int u = 0; u < 8; ++u) {
        float4 v = cp[u];
        vals[u * 4 + 0] = v.x; vals[u * 4 + 1] = v.y; vals[u * 4 + 2] = v.z; vals[u * 4 + 3] = v.w;
        m = fmaxf(m, fmaxf(fmaxf(v.x, v.y), fmaxf(v.z, v.w)));
    }
    float thr = m - CMARG;
    unsigned qm = 0;
    int c = 0;
    #pragma unroll
    for (int t = 0; t < 32; ++t) if (vals[t] >= thr) { qm |= 1u << t; ++c; }
    unsigned pos = atomicAdd(cnt, (unsigned)c);
    while (qm) { int t = __ffs(qm) - 1; qm &= qm - 1; list[pos++] = ((unsigned)n << 5) | (unsigned)t; }
}

// ---------------- exact np-f32 rescore of candidates (validated chain semantics) ----------------
__global__ __launch_bounds__(256) void vq_rescore(const float* __restrict__ X, const float* __restrict__ CB,
        const float* __restrict__ X2, const unsigned* __restrict__ Mk,
        const unsigned* __restrict__ list, const unsigned* __restrict__ cnt,
        unsigned long long* __restrict__ best64) {
    const int lw = threadIdx.x >> 6, lane = threadIdx.x & 63;
    unsigned c = *cnt;
    for (unsigned it = blockIdx.x * 4 + lw; it < c; it += gridDim.x * 4) {
        unsigned item = list[it];
        unsigned n = item >> 5, t = item & 31;
        const unsigned* mp = Mk + ((size_t)n * 32 + t) * 4;
        unsigned mw[4] = {mp[0], mp[1], mp[2], mp[3]};
        int nb = __popc(mw[0]) + __popc(mw[1]) + __popc(mw[2]) + __popc(mw[3]);
        const float* xr = X + (size_t)n * DIM;
        float x2 = X2[n];
        unsigned long long bestp = ~0ull;
        for (int base = 0; base < nb; base += 64) {
            int want = base + lane;
            int p = -1;
            if (want < nb) {
                int ww = want;
                #pragma unroll
                for (int wd = 0; wd < 4; ++wd) {
                    int pc = __popc(mw[wd]);
                    if (p < 0) {
                        if (ww < pc) {
                            unsigned mm = mw[wd];
                            for (int z = 0; z < ww; ++z) mm &= mm - 1;
                            p = wd * 32 + __ffs(mm) - 1;
                        } else ww -= pc;
                    }
                }
            }
            int k = (int)(t * 128) + ((p >= 0) ? p : 0);
            const float* er = CB + (size_t)k * DIM;
            float a = 0.f, b = 0.f;
            for (int d = 0; d < 384; ++d) a = fmaf(xr[d], er[d], a);
            for (int d = 384; d < 512; ++d) b = fmaf(xr[d], er[d], b);
            float D = fmaf(-2.f, __fadd_rn(a, b), x2);
            if (p >= 0) {
                unsigned long long pk = ((unsigned long long)__float_as_uint(D) << 32) | (unsigned)k;
                if (pk < bestp) bestp = pk;
            }
        }
        #pragma unroll
        for (int s = 1; s < 64; s <<= 1) {
            unsigned long long o = __shfl_xor(bestp, s);
            if (o < bestp) bestp = o;
        }
        if (lane == 0) atomicMin(best64 + n, bestp);
    }
}

// ---------------- gather + straight-through + loss (validated) ----------------
__global__ __launch_bounds__(256) void vq_out2(const float* __restrict__ X,
        const float* __restrict__ CB, const unsigned long long* __restrict__ best64,
        float* __restrict__ outq, float* __restrict__ outidx, float* __restrict__ lossAcc) {
    int tid = threadIdx.x;
    int token = blockIdx.x * 16 + (tid >> 4);
    int chunk = tid & 15;
    unsigned k = (unsigned)(best64[token] & 0xFFFFFFFFull);
    const float4* q4 = (const float4*)(CB + (size_t)k * DIM + chunk * 32);
    const float4* x4 = (const float4*)(X + (size_t)token * DIM + chunk * 32);
    float4* o4 = (float4*)(outq + (size_t)token * DIM + chunk * 32);
    float ls = 0.f;
    #pragma unroll
    for (int u = 0; u < 8; ++u) {
        float4 q = q4[u], xx = x4[u];
        float dx = q.x - xx.x, dy = q.y - xx.y, dz = q.z - xx.z, dw = q.w - xx.w;
        float4 o;
        o.x = xx.x + dx; o.y = xx.y + dy; o.z = xx.z + dz; o.w = xx.w + dw;
        o4[u] = o;
        ls += dx*dx + dy*dy + dz*dz + dw*dw;
    }
    if (chunk == 0) outidx[token] = (float)k;
    #pragma unroll
    for (int s = 1; s < 64; s <<= 1) ls += __shfl_xor(ls, s);
    __shared__ float red[4];
    if ((tid & 63) == 0) red[tid >> 6] = ls;
    __syncthreads();
    if (tid == 0) atomicAdd(lossAcc, red[0] + red[1] + red[2] + red[3]);
}

__global__ void vq_fin(const float* __restrict__ lossAcc, float* __restrict__ outloss) {
    *outloss = 1.1f * (*lossAcc) * (1.0f / 16777216.0f);
}

// ================= validated round-5 fallback path =================
__global__ __launch_bounds__(256) void vq_np2(const float* __restrict__ X,
        const float* __restrict__ CB, const float* __restrict__ X2,
        unsigned* __restrict__ idxA) {
    __shared__ __align__(16) float es[16][128];
    const int t = threadIdx.x;
    const int ty = t >> 4;
    const int tx = t & 15;
    const int n0 = blockIdx.x * 64;
    const int srow = t >> 1;
    const int scol = (t & 1) * 8;
    const float* xrow0 = X + (size_t)(n0 + ty * 4) * DIM;
    float x2v[4];
    #pragma unroll
    for (int i = 0; i < 4; ++i) x2v[i] = X2[n0 + ty * 4 + i];
    float best[4];
    unsigned bid[4];
    #pragma unroll
    for (int i = 0; i < 4; ++i) { best[i] = 3.0e38f; bid[i] = 0u; }
    float pv[8];
    {
        const float* p = CB + (size_t)srow * DIM + scol;
        *(float4*)&pv[0] = *(const float4*)(p);
        *(float4*)&pv[4] = *(const float4*)(p + 4);
    }
    for (int kt = 0; kt < K_CODES; kt += 128) {
        float accA[4][8], accB[4][8];
        #pragma unroll
        for (int i = 0; i < 4; ++i)
            #pragma unroll
            for (int j = 0; j < 8; ++j) { accA[i][j] = 0.f; accB[i][j] = 0.f; }
        for (int ch = 0; ch < 32; ++ch) {
            const int dt = ch * 16;
            float4 xv[4][4];
            #pragma unroll
            for (int i = 0; i < 4; ++i)
                #pragma unroll
                for (int u = 0; u < 4; ++u)
                    xv[i][u] = *(const float4*)(xrow0 + (size_t)i * DIM + dt + u * 4);
            __syncthreads();
            #pragma unroll
            for (int q = 0; q < 8; ++q) es[scol + q][srow] = pv[q];
            int nkt = kt, nch = ch + 1;
            if (nch == 32) { nch = 0; nkt += 128; }
            if (nkt < K_CODES) {
                const float* p = CB + (size_t)(nkt + srow) * DIM + nch * 16 + scol;
                *(float4*)&pv[0] = *(const float4*)(p);
                *(float4*)&pv[4] = *(const float4*)(p + 4);
            }
            __syncthreads();
            if (ch < 24) {
                #pragma unroll
                for (int d = 0; d < 16; ++d) {
                    const float4 e0 = *(const float4*)&es[d][tx * 4];
                    const float4 e1 = *(const float4*)&es[d][tx * 4 + 64];
                    const float eb[8] = {e0.x, e0.y, e0.z, e0.w, e1.x, e1.y, e1.z, e1.w};
                    #pragma unroll
                    for (int i = 0; i < 4; ++i) {
                        const float xd = ((const float*)&xv[i][0])[d];
                        #pragma unroll
                        for (int j = 0; j < 8; ++j) accA[i][j] = fmaf(xd, eb[j], accA[i][j]);
                    }
                }
            } else {
                #pragma unroll
                for (int d = 0; d < 16; ++d) {
                    const float4 e0 = *(const float4*)&es[d][tx * 4];
                    const float4 e1 = *(const float4*)&es[d][tx * 4 + 64];
                    const float eb[8] = {e0.x, e0.y, e0.z, e0.w, e1.x, e1.y, e1.z, e1.w};
                    #pragma unroll
                    for (int i = 0; i < 4; ++i) {
                        const float xd = ((const float*)&xv[i][0])[d];
                        #pragma unroll
                        for (int j = 0; j < 8; ++j) accB[i][j] = fmaf(xd, eb[j], accB[i][j]);
                    }
                }
            }
        }
        #pragma unroll
        for (int j = 0; j < 8; ++j) {
            const int k = kt + ((j < 4) ? (tx * 4 + j) : (64 + tx * 4 + j - 4));
            #pragma unroll
            for (int i = 0; i < 4; ++i) {
                float C = __fadd_rn(accA[i][j], accB[i][j]);
                float v = fmaf(-2.0f, C, x2v[i]);
                if (v < best[i]) { best[i] = v; bid[i] = (unsigned)k; }
            }
        }
    }
    #pragma unroll
    for (int i = 0; i < 4; ++i) {
        float v = best[i];
        unsigned id = bid[i];
        #pragma unroll
        for (int s = 1; s < 16; s <<= 1) {
            float ov = __shfl_xor(v, s);
            unsigned oid = __shfl_xor(id, s);
            if (ov < v || (ov == v && oid < id)) { v = ov; id = oid; }
        }
        if (tx == 0) idxA[n0 + ty * 4 + i] = id;
    }
}

__global__ __launch_bounds__(256) void vq_out(const float* __restrict__ X,
        const float* __restrict__ CB, const unsigned* __restrict__ idxA,
        float* __restrict__ outq, float* __restrict__ outidx, float* __restrict__ lossAcc) {
    int tid = threadIdx.x;
    int token = blockIdx.x * 16 + (tid >> 4);
    int chunk = tid & 15;
    unsigned k = idxA[token];
    const float4* q4 = (const float4*)(CB + (size_t)k * DIM + chunk * 32);
    const float4* x4 = (const float4*)(X + (size_t)token * DIM + chunk * 32);
    float4* o4 = (float4*)(outq + (size_t)token * DIM + chunk * 32);
    float ls = 0.f;
    #pragma unroll
    for (int u = 0; u < 8; ++u) {
        float4 q = q4[u], xx = x4[u];
        float dx = q.x - xx.x, dy = q.y - xx.y, dz = q.z - xx.z, dw = q.w - xx.w;
        float4 o;
        o.x = xx.x + dx; o.y = xx.y + dy; o.z = xx.z + dz; o.w = xx.w + dw;
        o4[u] = o;
        ls += dx*dx + dy*dy + dz*dz + dw*dw;
    }
    if (chunk == 0) outidx[token] = (float)k;
    #pragma unroll
    for (int s = 1; s < 64; s <<= 1) ls += __shfl_xor(ls, s);
    __shared__ float red[4];
    if ((tid & 63) == 0) red[tid >> 6] = ls;
    __syncthreads();
    if (tid == 0) atomicAdd(lossAcc, red[0] + red[1] + red[2] + red[3]);
}

extern "C" void kernel_launch(void* const* d_in, const int* in_sizes, int n_in,
                              void* d_out, int out_size, void* d_ws, size_t ws_size,
                              hipStream_t stream) {
    const float* X  = (const float*)d_in[0];
    const float* CB = (const float*)d_in[1];
    float* out = (float*)d_out;
    float* outq    = out;
    float* outloss = out + (size_t)N_TOK * DIM;
    float* outidx  = out + (size_t)N_TOK * DIM + 1;

    char* w = (char*)d_ws;
    unsigned* cnt  = (unsigned*)w;
    float* lossAcc = (float*)(w + 4);
    float* X2      = (float*)(w + 256);
    unsigned short* Ah = (unsigned short*)(w + 262144);
    unsigned short* Al = (unsigned short*)(w + 33816576);
    unsigned short* Eh = (unsigned short*)(w + 67371008);
    unsigned short* El = (unsigned short*)(w + 71565312);
    float* Cm          = (float*)(w + 75759616);
    unsigned* Mk       = (unsigned*)(w + 79953920);
    unsigned long long* best64 = (unsigned long long*)(w + 96731136);
    unsigned* list     = (unsigned*)(w + 96993280);
    const size_t WS_NEED = 101187584;

    if (ws_size >= WS_NEED) {
        hipMemsetAsync(d_ws, 0, 64, stream);
        hipMemsetAsync(best64, 0xFF, (size_t)N_TOK * 8, stream);
        vq_x2<<<N_TOK / 256, 256, 0, stream>>>(X, X2);
        vq_split<<<(N_TOK + K_CODES) * DIM / 8 / 256, 256, 0, stream>>>(X, CB, Ah, Al, Eh, El);
        dim3 gg(N_TOK / 128, K_CODES / 128);
        vq_gemm<<<gg, 256, 0, stream>>>(Ah, Al, Eh, El, Cm, Mk);
        vq_scan<<<N_TOK / 256, 256, 0, stream>>>(Cm, list, cnt);
        vq_rescore<<<2048, 256, 0, stream>>>(X, CB, X2, Mk, list, cnt, best64);
        vq_out2<<<N_TOK / 16, 256, 0, stream>>>(X, CB, best64, outq, outidx, lossAcc);
        vq_fin<<<1, 1, 0, stream>>>(lossAcc, outloss);
    } else {
        // validated round-5 fallback
        float* X2f     = (float*)(w + 64);
        unsigned* idxA = (unsigned*)(w + 64 + 131072);
        hipMemsetAsync(d_ws, 0, 64, stream);
        vq_x2<<<N_TOK / 256, 256, 0, stream>>>(X, X2f);
        vq_np2<<<N_TOK / 64, 256, 0, stream>>>(X, CB, X2f, idxA);
        vq_out<<<N_TOK / 16, 256, 0, stream>>>(X, CB, idxA, outq, outidx, lossAcc);
        vq_fin<<<1, 1, 0, stream>>>(lossAcc, outloss);
    }
}